// Round 9
// baseline (453.370 us; speedup 1.0000x reference)
//
#include <hip/hip_runtime.h>
#include <hip/hip_bf16.h>

#define N_NODES 20000
#define N_EDGES 320000
#define N_ADJ   4
#define D       256
#define DH      128              // packed bf16x2 dwords per feature row
#define RPA     20004            // row_ptr stride per adjacency (20001 rounded to x4)

#define HB      160              // hist/scatter blocks per adjacency
#define EPB2    2000             // edges per block (160 * 2000 = 320000)
#define MMBLK   1250             // matmul blocks (16-row tiles)

typedef __attribute__((ext_vector_type(8))) short bf8;   // 8 bf16 (4 VGPRs)
typedef __attribute__((ext_vector_type(4))) float f4;    // MFMA accumulator

// ---------------------------------------------------------------------------
// bf16 pack/unpack helpers (RNE rounding; values are finite)
// ---------------------------------------------------------------------------

__device__ __forceinline__ unsigned f2bf_bits(float x) {
    unsigned u = __float_as_uint(x);
    return (u + 0x7FFFu + ((u >> 16) & 1u)) >> 16;
}
__device__ __forceinline__ unsigned pack_bf2(float lo, float hi) {
    return f2bf_bits(lo) | (f2bf_bits(hi) << 16);
}
__device__ __forceinline__ float bf_lo(unsigned p) { return __uint_as_float(p << 16); }
__device__ __forceinline__ float bf_hi(unsigned p) { return __uint_as_float(p & 0xFFFF0000u); }

// ---------------------------------------------------------------------------
// hist_kernel: per-(adj,row) degree histogram via GLOBAL atomics (80000 hot
// words, L2-resident -> few-us L2-atomic throughput; replaces the 2-hop
// LDS-staging prep whose append+bsort pipeline cost ~100+ us).
// wfrag path fused on 2 extra blocks (a==0): W -> fragment-ordered bf16
// hi/lo tables, unchanged from prep.
// ---------------------------------------------------------------------------

__global__ __launch_bounds__(1024) void hist_kernel(const int* __restrict__ rows,
                                                    int* __restrict__ cnt,
                                                    const float* __restrict__ W,
                                                    uint4* __restrict__ wh,
                                                    uint4* __restrict__ wl) {
    int g = blockIdx.x, a = blockIdx.y, t = threadIdx.x;

    if (g >= HB) {                            // ---- wfrag path (2 blocks, a==0)
        if (a != 0) return;
        for (int i = (g - HB) * 1024 + t; i < 8192; i += 2048) {
            int lane = i & 63;
            int tile = i >> 6;                // ks*16 + n
            int ks = tile >> 4, n = tile & 15;
            int m = lane & 15, quad = lane >> 4;
            int col = n * 16 + m;
            int k0  = ks * 32 + quad * 8;
            unsigned hbits[8], lbits[8];
            #pragma unroll
            for (int j = 0; j < 8; ++j) {
                float v = W[(k0 + j) * D + col];
                unsigned hb = f2bf_bits(v);
                float lo = v - __uint_as_float(hb << 16);
                hbits[j] = hb;
                lbits[j] = f2bf_bits(lo);
            }
            uint4 hh, ll;
            hh.x = hbits[0] | (hbits[1] << 16); hh.y = hbits[2] | (hbits[3] << 16);
            hh.z = hbits[4] | (hbits[5] << 16); hh.w = hbits[6] | (hbits[7] << 16);
            ll.x = lbits[0] | (lbits[1] << 16); ll.y = lbits[2] | (lbits[3] << 16);
            ll.z = lbits[4] | (lbits[5] << 16); ll.w = lbits[6] | (lbits[7] << 16);
            wh[i] = hh;
            wl[i] = ll;
        }
        return;
    }

    int e0 = a * N_EDGES + g * EPB2;
    for (int i = t; i < EPB2; i += 1024) {
        int r = rows[e0 + i];
        atomicAdd(&cnt[a * N_NODES + r], 1);
    }
}

// ---------------------------------------------------------------------------
// scan_kernel: one block per adjacency.  Each thread owns 20 rows; block
// Hillis-Steele over the 1024 per-thread sums; writes row_ptr AND resets
// cnt[a][r] to the row base so scatter's atomicAdd returns final positions.
// ---------------------------------------------------------------------------

__global__ __launch_bounds__(1024) void scan_kernel(int* __restrict__ cnt,
                                                    int* __restrict__ row_ptr) {
    __shared__ int ts[1024];
    int a = blockIdx.x, t = threadIdx.x;
    int base = t * 20;
    int* ca = cnt + a * N_NODES;
    int loc[20];
    int sum = 0;
    #pragma unroll
    for (int j = 0; j < 20; ++j) {
        int r = base + j;
        int v = (r < N_NODES) ? ca[r] : 0;
        loc[j] = sum;
        sum += v;
    }
    ts[t] = sum;
    __syncthreads();
    for (int off = 1; off < 1024; off <<= 1) {
        int add = (t >= off) ? ts[t - off] : 0;
        __syncthreads();
        ts[t] += add;
        __syncthreads();
    }
    int excl = ts[t] - sum;
    int* rp = row_ptr + (size_t)a * RPA;
    #pragma unroll
    for (int j = 0; j < 20; ++j) {
        int r = base + j;
        if (r < N_NODES) {
            int bofs = excl + loc[j];
            rp[r] = bofs;
            ca[r] = bofs;                 // scatter base
        }
    }
    if (t == 0) rp[N_NODES] = N_EDGES;
}

// ---------------------------------------------------------------------------
// scatter_kernel: re-read edges, take a position with one global atomic,
// write the 4 B CSR record (bf16 weight | source col).  Within-row order is
// nondeterministic (atomic) -- a bounded fp32 reorder, numerically benign.
// ---------------------------------------------------------------------------

__global__ __launch_bounds__(1024) void scatter_kernel(const int* __restrict__ rows,
                                                       const int* __restrict__ cols,
                                                       const float* __restrict__ vals,
                                                       int* __restrict__ cnt,
                                                       unsigned* __restrict__ csr) {
    int g = blockIdx.x, a = blockIdx.y, t = threadIdx.x;
    int e0 = a * N_EDGES + g * EPB2;
    for (int i = t; i < EPB2; i += 1024) {
        int e = e0 + i;
        int r   = rows[e];
        int c   = cols[e];
        float v = vals[e];
        int pos = atomicAdd(&cnt[a * N_NODES + r], 1);
        csr[(size_t)a * N_EDGES + pos] = (f2bf_bits(v) << 16) | (unsigned)c;
    }
}

// ---------------------------------------------------------------------------
// mm_kernel: h = x @ W + b via bf16 MFMA hi/lo compensation (f32-accurate).
// One block per 16-row tile; zero LDS -> full occupancy.
// ---------------------------------------------------------------------------

__global__ __launch_bounds__(256) void mm_kernel(const float* __restrict__ x,
                                                 const uint4* __restrict__ wh,
                                                 const uint4* __restrict__ wl,
                                                 const float* __restrict__ bvec,
                                                 unsigned* __restrict__ hp) {
    int t = threadIdx.x;
    int wid = t >> 6, lane = t & 63;
    int r0 = blockIdx.x * 16;             // 1250 * 16 = 20000 exactly
    int m = lane & 15, quad = lane >> 4;

    const float* xr = x + (size_t)(r0 + m) * D + quad * 8;
    bf8 ah[8], al[8];
    #pragma unroll
    for (int ks = 0; ks < 8; ++ks) {
        float4 v0 = *(const float4*)(xr + ks * 32);
        float4 v1 = *(const float4*)(xr + ks * 32 + 4);
        float xs[8] = {v0.x, v0.y, v0.z, v0.w, v1.x, v1.y, v1.z, v1.w};
        #pragma unroll
        for (int j = 0; j < 8; ++j) {
            unsigned hb = f2bf_bits(xs[j]);
            float lo = xs[j] - __uint_as_float(hb << 16);
            ah[ks][j] = (short)hb;
            al[ks][j] = (short)f2bf_bits(lo);
        }
    }

    #pragma unroll
    for (int i = 0; i < 4; ++i) {
        int n = wid * 4 + i;
        f4 c = {0.f, 0.f, 0.f, 0.f};
        #pragma unroll
        for (int ks = 0; ks < 8; ++ks) {
            uint4 bh4 = wh[(ks * 16 + n) * 64 + lane];
            uint4 bl4 = wl[(ks * 16 + n) * 64 + lane];
            bf8 bh = *(bf8*)&bh4;
            bf8 bl = *(bf8*)&bl4;
            c = __builtin_amdgcn_mfma_f32_16x16x32_bf16(ah[ks], bh, c, 0, 0, 0);
            c = __builtin_amdgcn_mfma_f32_16x16x32_bf16(al[ks], bh, c, 0, 0, 0);
            c = __builtin_amdgcn_mfma_f32_16x16x32_bf16(ah[ks], bl, c, 0, 0, 0);
        }
        int col = n * 16 + m;
        float bb = bvec[col];
        #pragma unroll
        for (int reg = 0; reg < 4; ++reg) {
            float v = c[reg] + bb;            // (r0+quad*4+reg, col)
            float o = __shfl_xor(v, 1, 64);   // partner column col^1
            if ((m & 1) == 0) {
                hp[(r0 + quad * 4 + reg) * DH + (col >> 1)] = pack_bf2(v, o);
            }
        }
    }
}

// ---------------------------------------------------------------------------
// Gather one (row, adj) segment.  ONE WAVE per row: lane owns features
// 4*lane..4*lane+3 (one uint2 = 2 packed dwords).  beg/end are wave-uniform
// (readfirstlane'd by caller).  8-deep pipeline (r0-proven: 71.3 us).
// ---------------------------------------------------------------------------

__device__ __forceinline__ void gather_seg(const unsigned* __restrict__ E, int beg, int end,
                                           const uint2* __restrict__ feat2, int lane,
                                           float* __restrict__ s /* [4] */) {
    int n = end - beg;
    const unsigned* e = E + beg;
    int m8 = n & ~7;
    if (m8) {
        unsigned rec[8];
        #pragma unroll
        for (int j = 0; j < 8; ++j) rec[j] = e[j];
        for (int i = 8; ; i += 8) {
            uint2 p[8];
            #pragma unroll
            for (int j = 0; j < 8; ++j)
                p[j] = feat2[((rec[j] & 0xFFFFu) << 6) + lane];
            bool more = i < m8;
            unsigned nrec[8];
            if (more) {
                #pragma unroll
                for (int j = 0; j < 8; ++j) nrec[j] = e[i + j];
            }
            #pragma unroll
            for (int j = 0; j < 8; ++j) {
                float v = __uint_as_float(rec[j] & 0xFFFF0000u);
                s[0] += v * bf_lo(p[j].x);
                s[1] += v * bf_hi(p[j].x);
                s[2] += v * bf_lo(p[j].y);
                s[3] += v * bf_hi(p[j].y);
            }
            if (!more) break;
            #pragma unroll
            for (int j = 0; j < 8; ++j) rec[j] = nrec[j];
        }
    }
    for (int i = m8; i < n; ++i) {
        unsigned rr = e[i];
        uint2 pp = feat2[((rr & 0xFFFFu) << 6) + lane];
        float vv = __uint_as_float(rr & 0xFFFF0000u);
        s[0] += vv * bf_lo(pp.x);
        s[1] += vv * bf_hi(pp.x);
        s[2] += vv * bf_lo(pp.y);
        s[3] += vv * bf_hi(pp.y);
    }
}

// ---------------------------------------------------------------------------
// Stage 1: input h (packed).  Emits s1, s2-partial (packed uint2), out-partial
// (f32 float4, into d_out).  4 waves per block = 4 rows.
// ---------------------------------------------------------------------------

__global__ __launch_bounds__(256) void stage1_kernel(const uint2* __restrict__ hp2,
                                                     const int* __restrict__ row_ptr,
                                                     const unsigned* __restrict__ csr,
                                                     const float* __restrict__ wseq0,
                                                     const float* __restrict__ wres0,
                                                     const float* __restrict__ wres1,
                                                     uint2* __restrict__ s1p2,
                                                     uint2* __restrict__ s2p2,
                                                     float4* __restrict__ outp4) {
    int t = threadIdx.x, wid = t >> 6, lane = t & 63;
    int r = blockIdx.x * 4 + wid;
    float acc[N_ADJ][4];
    #pragma unroll
    for (int a = 0; a < N_ADJ; ++a) {
        acc[a][0] = acc[a][1] = acc[a][2] = acc[a][3] = 0.f;
        const int* rp = row_ptr + (size_t)a * RPA;
        int beg = __builtin_amdgcn_readfirstlane(rp[r]);
        int end = __builtin_amdgcn_readfirstlane(rp[r + 1]);
        gather_seg(csr + (size_t)a * N_EDGES, beg, end, hp2, lane, acc[a]);
    }
    const float third = 1.f / 3.f;
    float w0 = wseq0[0] * third, w1 = wseq0[1] * third, w2 = wseq0[2] * third;
    float q0 = wres0[0] * 0.25f, q1 = wres0[1] * 0.25f, q2 = wres0[2] * 0.25f, q3 = wres0[3] * 0.25f;
    float u0 = wres1[0] * third, u1 = wres1[1] * third, u2 = wres1[2] * third;
    float s1v[4], s2v[4], ov[4];
    #pragma unroll
    for (int j = 0; j < 4; ++j) {
        s1v[j] = w0 * acc[0][j] + w1 * acc[1][j] + w2 * acc[2][j];
        s2v[j] = q0 * acc[0][j] + q1 * acc[1][j] + q2 * acc[2][j] + q3 * acc[3][j];
        ov[j]  = u0 * acc[0][j] + u1 * acc[1][j] + u2 * acc[3][j];
    }
    int o = r * 64 + lane;
    s1p2[o]  = make_uint2(pack_bf2(s1v[0], s1v[1]), pack_bf2(s1v[2], s1v[3]));
    s2p2[o]  = make_uint2(pack_bf2(s2v[0], s2v[1]), pack_bf2(s2v[2], s2v[3]));
    outp4[o] = make_float4(ov[0], ov[1], ov[2], ov[3]);
}

// ---------------------------------------------------------------------------
// Stage 2: input s1 (packed).  s2 += seq-combo; out-partial += res-combo.
// ---------------------------------------------------------------------------

__global__ __launch_bounds__(256) void stage2_kernel(const uint2* __restrict__ s1p2,
                                                     const int* __restrict__ row_ptr,
                                                     const unsigned* __restrict__ csr,
                                                     const float* __restrict__ wseq0,
                                                     const float* __restrict__ wres1,
                                                     uint2* __restrict__ s2p2,
                                                     float4* __restrict__ outp4) {
    int t = threadIdx.x, wid = t >> 6, lane = t & 63;
    int r = blockIdx.x * 4 + wid;
    float acc[N_ADJ][4];
    #pragma unroll
    for (int a = 0; a < N_ADJ; ++a) {
        acc[a][0] = acc[a][1] = acc[a][2] = acc[a][3] = 0.f;
        const int* rp = row_ptr + (size_t)a * RPA;
        int beg = __builtin_amdgcn_readfirstlane(rp[r]);
        int end = __builtin_amdgcn_readfirstlane(rp[r + 1]);
        gather_seg(csr + (size_t)a * N_EDGES, beg, end, s1p2, lane, acc[a]);
    }
    const float third = 1.f / 3.f;
    float w3 = wseq0[3] * third, w4 = wseq0[4] * third, w5 = wseq0[5] * third;
    float u3 = wres1[3] * third, u4 = wres1[4] * third, u5 = wres1[5] * third;
    int o = r * 64 + lane;
    uint2 sp = s2p2[o];
    float c0 = bf_lo(sp.x) + w3 * acc[0][0] + w4 * acc[1][0] + w5 * acc[2][0];
    float c1 = bf_hi(sp.x) + w3 * acc[0][1] + w4 * acc[1][1] + w5 * acc[2][1];
    float c2 = bf_lo(sp.y) + w3 * acc[0][2] + w4 * acc[1][2] + w5 * acc[2][2];
    float c3 = bf_hi(sp.y) + w3 * acc[0][3] + w4 * acc[1][3] + w5 * acc[2][3];
    s2p2[o] = make_uint2(pack_bf2(c0, c1), pack_bf2(c2, c3));
    float4 op = outp4[o];
    op.x += u3 * acc[0][0] + u4 * acc[1][0] + u5 * acc[3][0];
    op.y += u3 * acc[0][1] + u4 * acc[1][1] + u5 * acc[3][1];
    op.z += u3 * acc[0][2] + u4 * acc[1][2] + u5 * acc[3][2];
    op.w += u3 * acc[0][3] + u4 * acc[1][3] + u5 * acc[3][3];
    outp4[o] = op;
}

// ---------------------------------------------------------------------------
// Stage 3: input s2 (adjacencies 0,1), add out-partial, LayerNorm (pure wave
// shuffle reduction -- no LDS, no syncthreads), exact GELU.
// ---------------------------------------------------------------------------

__global__ __launch_bounds__(256) void stage3_kernel(const uint2* __restrict__ s2p2,
                                                     const int* __restrict__ row_ptr,
                                                     const unsigned* __restrict__ csr,
                                                     const float* __restrict__ wseq1,
                                                     float4* __restrict__ outp4) {
    int t = threadIdx.x, wid = t >> 6, lane = t & 63;
    int r = blockIdx.x * 4 + wid;
    float acc[2][4];
    #pragma unroll
    for (int a = 0; a < 2; ++a) {
        acc[a][0] = acc[a][1] = acc[a][2] = acc[a][3] = 0.f;
        const int* rp = row_ptr + (size_t)a * RPA;
        int beg = __builtin_amdgcn_readfirstlane(rp[r]);
        int end = __builtin_amdgcn_readfirstlane(rp[r + 1]);
        gather_seg(csr + (size_t)a * N_EDGES, beg, end, s2p2, lane, acc[a]);
    }
    float e0 = wseq1[0] * 0.5f, e1 = wseq1[1] * 0.5f;
    int o = r * 64 + lane;
    float4 op = outp4[o];
    float v0 = op.x + e0 * acc[0][0] + e1 * acc[1][0];
    float v1 = op.y + e0 * acc[0][1] + e1 * acc[1][1];
    float v2 = op.z + e0 * acc[0][2] + e1 * acc[1][2];
    float v3 = op.w + e0 * acc[0][3] + e1 * acc[1][3];

    float sv = v0 + v1 + v2 + v3;
    float sq = v0 * v0 + v1 * v1 + v2 * v2 + v3 * v3;
    #pragma unroll
    for (int off = 32; off > 0; off >>= 1) {
        sv += __shfl_xor(sv, off, 64);
        sq += __shfl_xor(sq, off, 64);
    }
    float mu   = sv * (1.f / 256.f);
    float var  = sq * (1.f / 256.f) - mu * mu;
    float rstd = rsqrtf(var + 1e-5f);
    float y0 = (v0 - mu) * rstd;
    float y1 = (v1 - mu) * rstd;
    float y2 = (v2 - mu) * rstd;
    float y3 = (v3 - mu) * rstd;
    const float is2 = 0.70710678118654752440f;
    outp4[o] = make_float4(0.5f * y0 * (1.f + erff(y0 * is2)),
                           0.5f * y1 * (1.f + erff(y1 * is2)),
                           0.5f * y2 * (1.f + erff(y2 * is2)),
                           0.5f * y3 * (1.f + erff(y3 * is2)));
}

// ---------------------------------------------------------------------------

extern "C" void kernel_launch(void* const* d_in, const int* in_sizes, int n_in,
                              void* d_out, int out_size, void* d_ws, size_t ws_size,
                              hipStream_t stream) {
    const float* x     = (const float*)d_in[0];
    const int*   rows  = (const int*)d_in[1];
    const int*   cols  = (const int*)d_in[2];
    const float* vals  = (const float*)d_in[3];
    const float* W     = (const float*)d_in[4];
    const float* b     = (const float*)d_in[5];
    const float* wseq0 = (const float*)d_in[6];  // (2,3)
    const float* wseq1 = (const float*)d_in[7];  // (2,)
    const float* wres0 = (const float*)d_in[8];  // (1,4)
    const float* wres1 = (const float*)d_in[9];  // (2,3)
    float4* outp4 = (float4*)d_out;

    char* p = (char*)d_ws;
    unsigned* hp  = (unsigned*)p; p += (size_t)N_NODES * DH * 4;      // 10.24 MB
    unsigned* s1p = (unsigned*)p; p += (size_t)N_NODES * DH * 4;      // 10.24 MB
    unsigned* s2p = (unsigned*)p; p += (size_t)N_NODES * DH * 4;      // 10.24 MB
    int* row_ptr  = (int*)p;      p += (size_t)N_ADJ * RPA * 4;       // 320 KB
    uint4* wh     = (uint4*)p;    p += 8192 * 16;                     // 128 KB
    uint4* wl     = (uint4*)p;    p += 8192 * 16;                     // 128 KB
    unsigned* csr = (unsigned*)p;                                     // 5.12 MB
    // cnt (4 x 20000 ints = 320 KB) overlays s1p: its lifetime (hist->scan->
    // scatter) ends before stage1 writes s1p.
    int* cnt = (int*)s1p;

    hipMemsetAsync(cnt, 0, (size_t)N_ADJ * N_NODES * 4, stream);
    // hist (+wfrag on 2 extra blocks) -> scan -> scatter: global-atomic CSR
    hist_kernel<<<dim3(HB + 2, N_ADJ), 1024, 0, stream>>>(rows, cnt, W, wh, wl);
    scan_kernel<<<N_ADJ, 1024, 0, stream>>>(cnt, row_ptr);
    scatter_kernel<<<dim3(HB, N_ADJ), 1024, 0, stream>>>(rows, cols, vals, cnt, csr);
    mm_kernel<<<MMBLK, 256, 0, stream>>>(x, wh, wl, b, hp);

    stage1_kernel<<<N_NODES / 4, 256, 0, stream>>>((const uint2*)hp, row_ptr, csr,
                                                   wseq0, wres0, wres1,
                                                   (uint2*)s1p, (uint2*)s2p, outp4);
    stage2_kernel<<<N_NODES / 4, 256, 0, stream>>>((const uint2*)s1p, row_ptr, csr,
                                                   wseq0, wres1, (uint2*)s2p, outp4);
    stage3_kernel<<<N_NODES / 4, 256, 0, stream>>>((const uint2*)s2p, row_ptr, csr,
                                                   wseq1, outp4);
}

// Round 10
// 337.739 us; speedup vs baseline: 1.3424x; 1.3424x over previous
//
#include <hip/hip_runtime.h>
#include <hip/hip_bf16.h>

#define N_NODES 20000
#define N_EDGES 320000
#define N_ADJ   4
#define D       256
#define DH      128              // packed bf16x2 dwords per feature row
#define RPA     20004            // row_ptr stride per adjacency (20001 rounded to x4)

// bucketed CSR build (block-private staging: NO global atomics -- r9 proved
// device-wide random atomics cost ~100ns each via cross-XCD line ping-pong)
#define NBUCK   313              // buckets of 64 rows (20000/64 -> 313)
#define NGRP    40               // staging groups = append blocks per adjacency
#define EPB     8000             // edges per append block (40 * 8000 = 320000)
#define GCAP    72               // cap per (adj,bucket,block) cell: mu=25.6, +9.2sd
#define MMBLK   1250             // matmul blocks (16-row tiles)

typedef __attribute__((ext_vector_type(8))) short bf8;   // 8 bf16 (4 VGPRs)
typedef __attribute__((ext_vector_type(4))) float f4;    // MFMA accumulator

// ---------------------------------------------------------------------------
// bf16 pack/unpack helpers (RNE rounding; values are finite)
// ---------------------------------------------------------------------------

__device__ __forceinline__ unsigned f2bf_bits(float x) {
    unsigned u = __float_as_uint(x);
    return (u + 0x7FFFu + ((u >> 16) & 1u)) >> 16;
}
__device__ __forceinline__ unsigned pack_bf2(float lo, float hi) {
    return f2bf_bits(lo) | (f2bf_bits(hi) << 16);
}
__device__ __forceinline__ float bf_lo(unsigned p) { return __uint_as_float(p << 16); }
__device__ __forceinline__ float bf_hi(unsigned p) { return __uint_as_float(p & 0xFFFF0000u); }

// ---------------------------------------------------------------------------
// prep_kernel: append (blocks g<40, all a) PARALLEL wfrag (g>=40, a==0).
// append: edges -> block-private (adj,bucket,block) staging cells via LDS
// atomics.  64-row buckets: 313 LDS counters -> ~2 threads/counter per
// iteration (vs 13 with 79 counters) = ~4x less atomic serialization.
// wfrag: W -> fragment-ordered bf16 hi/lo tables, grid-strided on 2 blocks.
// ---------------------------------------------------------------------------

__global__ __launch_bounds__(1024) void prep_kernel(const int* __restrict__ rows,
                                                    const int* __restrict__ cols,
                                                    const float* __restrict__ vals,
                                                    int* __restrict__ cnt,
                                                    uint2* __restrict__ stage,
                                                    const float* __restrict__ W,
                                                    uint4* __restrict__ wh,
                                                    uint4* __restrict__ wl) {
    __shared__ int lcnt[NBUCK];
    int g = blockIdx.x, a = blockIdx.y, t = threadIdx.x;

    if (g >= NGRP) {                          // ---- wfrag path (2 blocks, a==0)
        if (a != 0) return;
        for (int i = (g - NGRP) * 1024 + t; i < 8192; i += 2048) {
            int lane = i & 63;
            int tile = i >> 6;                // ks*16 + n
            int ks = tile >> 4, n = tile & 15;
            int m = lane & 15, quad = lane >> 4;
            int col = n * 16 + m;
            int k0  = ks * 32 + quad * 8;
            unsigned hbits[8], lbits[8];
            #pragma unroll
            for (int j = 0; j < 8; ++j) {
                float v = W[(k0 + j) * D + col];
                unsigned hb = f2bf_bits(v);
                float lo = v - __uint_as_float(hb << 16);
                hbits[j] = hb;
                lbits[j] = f2bf_bits(lo);
            }
            uint4 hh, ll;
            hh.x = hbits[0] | (hbits[1] << 16); hh.y = hbits[2] | (hbits[3] << 16);
            hh.z = hbits[4] | (hbits[5] << 16); hh.w = hbits[6] | (hbits[7] << 16);
            ll.x = lbits[0] | (lbits[1] << 16); ll.y = lbits[2] | (lbits[3] << 16);
            ll.z = lbits[4] | (lbits[5] << 16); ll.w = lbits[6] | (lbits[7] << 16);
            wh[i] = hh;
            wl[i] = ll;
        }
        return;
    }

    // ---- append path
    if (t < NBUCK) lcnt[t] = 0;
    __syncthreads();
    int e0 = g * EPB;
    #pragma unroll 1
    for (int i = 0; i < EPB; i += 1024) {
        int e = e0 + i + t;
        if (i + t < EPB) {
            int r   = rows[a * N_EDGES + e];
            int c   = cols[a * N_EDGES + e];
            float v = vals[a * N_EDGES + e];
            int b   = r >> 6;
            int idx = atomicAdd(&lcnt[b], 1);     // LDS atomic
            if (idx < GCAP) {
                stage[(size_t)((a * NBUCK + b) * NGRP + g) * GCAP + idx] =
                    make_uint2((f2bf_bits(v) << 16) | (unsigned)c, (unsigned)(r & 63));
            }
        }
    }
    __syncthreads();
    if (t < NBUCK) cnt[(a * NBUCK + t) * NGRP + g] = min(lcnt[t], GCAP);
}

// ---------------------------------------------------------------------------
// bsort_kernel: one block per (adj,64-row-bucket) = 1252 blocks (vs 316 with
// 256-row buckets -- bsort was parallelism-starved at 1.2 blocks/CU).
// No LDS record buffer: pass 1 counts records straight from L2-hot staging,
// 64-bin scan, pass 2 re-reads and writes final CSR.  ~1 KB LDS.
// ---------------------------------------------------------------------------

__global__ __launch_bounds__(256) void bsort_kernel(const int* __restrict__ cnt,
                                                    const uint2* __restrict__ stage,
                                                    unsigned* __restrict__ csr,
                                                    int* __restrict__ row_ptr) {
    __shared__ int scn[64];
    __shared__ int offs[64];
    __shared__ int gbase_s;
    int t = threadIdx.x;

    int linear = blockIdx.x;                  // 0..1251
    int a = linear / NBUCK, b = linear % NBUCK;

    if (t == 0) gbase_s = 0;
    if (t < 64) { scn[t] = 0; offs[t] = 0; }
    __syncthreads();

    // global bucket base: sum of cnt[a][b'<b][*] (contiguous b*NGRP ints)
    int part = 0;
    for (int i = t; i < b * NGRP; i += 256) part += cnt[a * (NBUCK * NGRP) + i];
    #pragma unroll
    for (int off = 32; off > 0; off >>= 1) part += __shfl_xor(part, off, 64);
    if ((t & 63) == 0) atomicAdd(&gbase_s, part);

    // pass 1: per-localrow counts (records stay in L2; no LDS copy)
    const int* cb = cnt + (size_t)(a * NBUCK + b) * NGRP;
    #pragma unroll 1
    for (int g = 0; g < NGRP; ++g) {
        int c = cb[g];
        const uint2* src = stage + (size_t)((a * NBUCK + b) * NGRP + g) * GCAP;
        for (int i = t; i < c; i += 256) atomicAdd(&scn[src[i].y], 1);
    }
    __syncthreads();

    // inclusive scan over the 64 bins (Hillis-Steele in LDS)
    int mycnt = (t < 64) ? scn[t] : 0;
    for (int off = 1; off < 64; off <<= 1) {
        int add = (t >= off && t < 64) ? scn[t - off] : 0;
        __syncthreads();
        if (t < 64) scn[t] += add;
        __syncthreads();
    }
    int excl = (t < 64) ? scn[t] - mycnt : 0;
    __syncthreads();
    if (t < 64) scn[t] = excl;                // publish exclusive bases
    __syncthreads();

    int gbase = gbase_s;
    // pass 2: scatter records to final CSR positions
    #pragma unroll 1
    for (int g = 0; g < NGRP; ++g) {
        int c = cb[g];
        const uint2* src = stage + (size_t)((a * NBUCK + b) * NGRP + g) * GCAP;
        for (int i = t; i < c; i += 256) {
            uint2 rec = src[i];
            int pos = scn[rec.y] + atomicAdd(&offs[rec.y], 1);
            csr[(size_t)a * N_EDGES + gbase + pos] = rec.x;
        }
    }
    int r = b * 64 + t;
    if (t < 64 && r <= N_NODES) row_ptr[(size_t)a * RPA + r] = gbase + excl;
}

// ---------------------------------------------------------------------------
// mm_kernel: h = x @ W + b via bf16 MFMA hi/lo compensation (f32-accurate).
// One block per 16-row tile; zero LDS -> full occupancy.  Runs AFTER bsort
// so the staging overlay on hp is dead before hp is written.
// ---------------------------------------------------------------------------

__global__ __launch_bounds__(256) void mm_kernel(const float* __restrict__ x,
                                                 const uint4* __restrict__ wh,
                                                 const uint4* __restrict__ wl,
                                                 const float* __restrict__ bvec,
                                                 unsigned* __restrict__ hp) {
    int t = threadIdx.x;
    int wid = t >> 6, lane = t & 63;
    int r0 = blockIdx.x * 16;             // 1250 * 16 = 20000 exactly
    int m = lane & 15, quad = lane >> 4;

    const float* xr = x + (size_t)(r0 + m) * D + quad * 8;
    bf8 ah[8], al[8];
    #pragma unroll
    for (int ks = 0; ks < 8; ++ks) {
        float4 v0 = *(const float4*)(xr + ks * 32);
        float4 v1 = *(const float4*)(xr + ks * 32 + 4);
        float xs[8] = {v0.x, v0.y, v0.z, v0.w, v1.x, v1.y, v1.z, v1.w};
        #pragma unroll
        for (int j = 0; j < 8; ++j) {
            unsigned hb = f2bf_bits(xs[j]);
            float lo = xs[j] - __uint_as_float(hb << 16);
            ah[ks][j] = (short)hb;
            al[ks][j] = (short)f2bf_bits(lo);
        }
    }

    #pragma unroll
    for (int i = 0; i < 4; ++i) {
        int n = wid * 4 + i;
        f4 c = {0.f, 0.f, 0.f, 0.f};
        #pragma unroll
        for (int ks = 0; ks < 8; ++ks) {
            uint4 bh4 = wh[(ks * 16 + n) * 64 + lane];
            uint4 bl4 = wl[(ks * 16 + n) * 64 + lane];
            bf8 bh = *(bf8*)&bh4;
            bf8 bl = *(bf8*)&bl4;
            c = __builtin_amdgcn_mfma_f32_16x16x32_bf16(ah[ks], bh, c, 0, 0, 0);
            c = __builtin_amdgcn_mfma_f32_16x16x32_bf16(al[ks], bh, c, 0, 0, 0);
            c = __builtin_amdgcn_mfma_f32_16x16x32_bf16(ah[ks], bl, c, 0, 0, 0);
        }
        int col = n * 16 + m;
        float bb = bvec[col];
        #pragma unroll
        for (int reg = 0; reg < 4; ++reg) {
            float v = c[reg] + bb;            // (r0+quad*4+reg, col)
            float o = __shfl_xor(v, 1, 64);   // partner column col^1
            if ((m & 1) == 0) {
                hp[(r0 + quad * 4 + reg) * DH + (col >> 1)] = pack_bf2(v, o);
            }
        }
    }
}

// ---------------------------------------------------------------------------
// Gather one (row, adj) segment.  ONE WAVE per row: lane owns features
// 4*lane..4*lane+3 (one uint2 = 2 packed dwords).  beg/end are wave-uniform
// (readfirstlane'd by caller).  8-deep pipeline (r0-proven: 71.3 us).
// ---------------------------------------------------------------------------

__device__ __forceinline__ void gather_seg(const unsigned* __restrict__ E, int beg, int end,
                                           const uint2* __restrict__ feat2, int lane,
                                           float* __restrict__ s /* [4] */) {
    int n = end - beg;
    const unsigned* e = E + beg;
    int m8 = n & ~7;
    if (m8) {
        unsigned rec[8];
        #pragma unroll
        for (int j = 0; j < 8; ++j) rec[j] = e[j];
        for (int i = 8; ; i += 8) {
            uint2 p[8];
            #pragma unroll
            for (int j = 0; j < 8; ++j)
                p[j] = feat2[((rec[j] & 0xFFFFu) << 6) + lane];
            bool more = i < m8;
            unsigned nrec[8];
            if (more) {
                #pragma unroll
                for (int j = 0; j < 8; ++j) nrec[j] = e[i + j];
            }
            #pragma unroll
            for (int j = 0; j < 8; ++j) {
                float v = __uint_as_float(rec[j] & 0xFFFF0000u);
                s[0] += v * bf_lo(p[j].x);
                s[1] += v * bf_hi(p[j].x);
                s[2] += v * bf_lo(p[j].y);
                s[3] += v * bf_hi(p[j].y);
            }
            if (!more) break;
            #pragma unroll
            for (int j = 0; j < 8; ++j) rec[j] = nrec[j];
        }
    }
    for (int i = m8; i < n; ++i) {
        unsigned rr = e[i];
        uint2 pp = feat2[((rr & 0xFFFFu) << 6) + lane];
        float vv = __uint_as_float(rr & 0xFFFF0000u);
        s[0] += vv * bf_lo(pp.x);
        s[1] += vv * bf_hi(pp.x);
        s[2] += vv * bf_lo(pp.y);
        s[3] += vv * bf_hi(pp.y);
    }
}

// ---------------------------------------------------------------------------
// Stage 1: input h (packed).  Emits s1, s2-partial (packed uint2), out-partial
// (f32 float4, into d_out).  4 waves per block = 4 rows.
// ---------------------------------------------------------------------------

__global__ __launch_bounds__(256) void stage1_kernel(const uint2* __restrict__ hp2,
                                                     const int* __restrict__ row_ptr,
                                                     const unsigned* __restrict__ csr,
                                                     const float* __restrict__ wseq0,
                                                     const float* __restrict__ wres0,
                                                     const float* __restrict__ wres1,
                                                     uint2* __restrict__ s1p2,
                                                     uint2* __restrict__ s2p2,
                                                     float4* __restrict__ outp4) {
    int t = threadIdx.x, wid = t >> 6, lane = t & 63;
    int r = blockIdx.x * 4 + wid;
    float acc[N_ADJ][4];
    #pragma unroll
    for (int a = 0; a < N_ADJ; ++a) {
        acc[a][0] = acc[a][1] = acc[a][2] = acc[a][3] = 0.f;
        const int* rp = row_ptr + (size_t)a * RPA;
        int beg = __builtin_amdgcn_readfirstlane(rp[r]);
        int end = __builtin_amdgcn_readfirstlane(rp[r + 1]);
        gather_seg(csr + (size_t)a * N_EDGES, beg, end, hp2, lane, acc[a]);
    }
    const float third = 1.f / 3.f;
    float w0 = wseq0[0] * third, w1 = wseq0[1] * third, w2 = wseq0[2] * third;
    float q0 = wres0[0] * 0.25f, q1 = wres0[1] * 0.25f, q2 = wres0[2] * 0.25f, q3 = wres0[3] * 0.25f;
    float u0 = wres1[0] * third, u1 = wres1[1] * third, u2 = wres1[2] * third;
    float s1v[4], s2v[4], ov[4];
    #pragma unroll
    for (int j = 0; j < 4; ++j) {
        s1v[j] = w0 * acc[0][j] + w1 * acc[1][j] + w2 * acc[2][j];
        s2v[j] = q0 * acc[0][j] + q1 * acc[1][j] + q2 * acc[2][j] + q3 * acc[3][j];
        ov[j]  = u0 * acc[0][j] + u1 * acc[1][j] + u2 * acc[3][j];
    }
    int o = r * 64 + lane;
    s1p2[o]  = make_uint2(pack_bf2(s1v[0], s1v[1]), pack_bf2(s1v[2], s1v[3]));
    s2p2[o]  = make_uint2(pack_bf2(s2v[0], s2v[1]), pack_bf2(s2v[2], s2v[3]));
    outp4[o] = make_float4(ov[0], ov[1], ov[2], ov[3]);
}

// ---------------------------------------------------------------------------
// Stage 2: input s1 (packed).  s2 += seq-combo; out-partial += res-combo.
// ---------------------------------------------------------------------------

__global__ __launch_bounds__(256) void stage2_kernel(const uint2* __restrict__ s1p2,
                                                     const int* __restrict__ row_ptr,
                                                     const unsigned* __restrict__ csr,
                                                     const float* __restrict__ wseq0,
                                                     const float* __restrict__ wres1,
                                                     uint2* __restrict__ s2p2,
                                                     float4* __restrict__ outp4) {
    int t = threadIdx.x, wid = t >> 6, lane = t & 63;
    int r = blockIdx.x * 4 + wid;
    float acc[N_ADJ][4];
    #pragma unroll
    for (int a = 0; a < N_ADJ; ++a) {
        acc[a][0] = acc[a][1] = acc[a][2] = acc[a][3] = 0.f;
        const int* rp = row_ptr + (size_t)a * RPA;
        int beg = __builtin_amdgcn_readfirstlane(rp[r]);
        int end = __builtin_amdgcn_readfirstlane(rp[r + 1]);
        gather_seg(csr + (size_t)a * N_EDGES, beg, end, s1p2, lane, acc[a]);
    }
    const float third = 1.f / 3.f;
    float w3 = wseq0[3] * third, w4 = wseq0[4] * third, w5 = wseq0[5] * third;
    float u3 = wres1[3] * third, u4 = wres1[4] * third, u5 = wres1[5] * third;
    int o = r * 64 + lane;
    uint2 sp = s2p2[o];
    float c0 = bf_lo(sp.x) + w3 * acc[0][0] + w4 * acc[1][0] + w5 * acc[2][0];
    float c1 = bf_hi(sp.x) + w3 * acc[0][1] + w4 * acc[1][1] + w5 * acc[2][1];
    float c2 = bf_lo(sp.y) + w3 * acc[0][2] + w4 * acc[1][2] + w5 * acc[2][2];
    float c3 = bf_hi(sp.y) + w3 * acc[0][3] + w4 * acc[1][3] + w5 * acc[2][3];
    s2p2[o] = make_uint2(pack_bf2(c0, c1), pack_bf2(c2, c3));
    float4 op = outp4[o];
    op.x += u3 * acc[0][0] + u4 * acc[1][0] + u5 * acc[3][0];
    op.y += u3 * acc[0][1] + u4 * acc[1][1] + u5 * acc[3][1];
    op.z += u3 * acc[0][2] + u4 * acc[1][2] + u5 * acc[3][2];
    op.w += u3 * acc[0][3] + u4 * acc[1][3] + u5 * acc[3][3];
    outp4[o] = op;
}

// ---------------------------------------------------------------------------
// Stage 3: input s2 (adjacencies 0,1), add out-partial, LayerNorm (pure wave
// shuffle reduction -- no LDS, no syncthreads), exact GELU.
// ---------------------------------------------------------------------------

__global__ __launch_bounds__(256) void stage3_kernel(const uint2* __restrict__ s2p2,
                                                     const int* __restrict__ row_ptr,
                                                     const unsigned* __restrict__ csr,
                                                     const float* __restrict__ wseq1,
                                                     float4* __restrict__ outp4) {
    int t = threadIdx.x, wid = t >> 6, lane = t & 63;
    int r = blockIdx.x * 4 + wid;
    float acc[2][4];
    #pragma unroll
    for (int a = 0; a < 2; ++a) {
        acc[a][0] = acc[a][1] = acc[a][2] = acc[a][3] = 0.f;
        const int* rp = row_ptr + (size_t)a * RPA;
        int beg = __builtin_amdgcn_readfirstlane(rp[r]);
        int end = __builtin_amdgcn_readfirstlane(rp[r + 1]);
        gather_seg(csr + (size_t)a * N_EDGES, beg, end, s2p2, lane, acc[a]);
    }
    float e0 = wseq1[0] * 0.5f, e1 = wseq1[1] * 0.5f;
    int o = r * 64 + lane;
    float4 op = outp4[o];
    float v0 = op.x + e0 * acc[0][0] + e1 * acc[1][0];
    float v1 = op.y + e0 * acc[0][1] + e1 * acc[1][1];
    float v2 = op.z + e0 * acc[0][2] + e1 * acc[1][2];
    float v3 = op.w + e0 * acc[0][3] + e1 * acc[1][3];

    float sv = v0 + v1 + v2 + v3;
    float sq = v0 * v0 + v1 * v1 + v2 * v2 + v3 * v3;
    #pragma unroll
    for (int off = 32; off > 0; off >>= 1) {
        sv += __shfl_xor(sv, off, 64);
        sq += __shfl_xor(sq, off, 64);
    }
    float mu   = sv * (1.f / 256.f);
    float var  = sq * (1.f / 256.f) - mu * mu;
    float rstd = rsqrtf(var + 1e-5f);
    float y0 = (v0 - mu) * rstd;
    float y1 = (v1 - mu) * rstd;
    float y2 = (v2 - mu) * rstd;
    float y3 = (v3 - mu) * rstd;
    const float is2 = 0.70710678118654752440f;
    outp4[o] = make_float4(0.5f * y0 * (1.f + erff(y0 * is2)),
                           0.5f * y1 * (1.f + erff(y1 * is2)),
                           0.5f * y2 * (1.f + erff(y2 * is2)),
                           0.5f * y3 * (1.f + erff(y3 * is2)));
}

// ---------------------------------------------------------------------------

extern "C" void kernel_launch(void* const* d_in, const int* in_sizes, int n_in,
                              void* d_out, int out_size, void* d_ws, size_t ws_size,
                              hipStream_t stream) {
    const float* x     = (const float*)d_in[0];
    const int*   rows  = (const int*)d_in[1];
    const int*   cols  = (const int*)d_in[2];
    const float* vals  = (const float*)d_in[3];
    const float* W     = (const float*)d_in[4];
    const float* b     = (const float*)d_in[5];
    const float* wseq0 = (const float*)d_in[6];  // (2,3)
    const float* wseq1 = (const float*)d_in[7];  // (2,)
    const float* wres0 = (const float*)d_in[8];  // (1,4)
    const float* wres1 = (const float*)d_in[9];  // (2,3)
    float4* outp4 = (float4*)d_out;

    char* p = (char*)d_ws;
    unsigned* hp  = (unsigned*)p; p += (size_t)N_NODES * DH * 4;      // 10.24 MB
    unsigned* s1p = (unsigned*)p; p += (size_t)N_NODES * DH * 4;      // 10.24 MB
    unsigned* s2p = (unsigned*)p; p += (size_t)N_NODES * DH * 4;      // 10.24 MB
    int* row_ptr  = (int*)p;      p += (size_t)N_ADJ * RPA * 4;       // 320 KB
    int* cnt      = (int*)p;      p += ((size_t)N_ADJ * NBUCK * NGRP * 4 + 127) / 128 * 128; // ~200 KB
    uint4* wh     = (uint4*)p;    p += 8192 * 16;                     // 128 KB
    uint4* wl     = (uint4*)p;    p += 8192 * 16;                     // 128 KB
    unsigned* csr = (unsigned*)p;                                     // 5.12 MB
    // staging overlays hp+s1p+s2p (30.72 MB available, 28.85 MB used):
    // consumed by bsort BEFORE mm writes hp (launch order is the barrier).
    uint2* stage  = (uint2*)hp;

    // prep: append (40 blocks/adj) + wfrag (2 extra blocks on adj row 0)
    prep_kernel<<<dim3(NGRP + 2, N_ADJ), 1024, 0, stream>>>(rows, cols, vals, cnt,
                                                            stage, W, wh, wl);
    // bsort first (consumes staging), then mm (writes hp over dead staging)
    bsort_kernel<<<NBUCK * N_ADJ, 256, 0, stream>>>(cnt, stage, csr, row_ptr);
    mm_kernel<<<MMBLK, 256, 0, stream>>>(x, wh, wl, b, hp);

    stage1_kernel<<<N_NODES / 4, 256, 0, stream>>>((const uint2*)hp, row_ptr, csr,
                                                   wseq0, wres0, wres1,
                                                   (uint2*)s1p, (uint2*)s2p, outp4);
    stage2_kernel<<<N_NODES / 4, 256, 0, stream>>>((const uint2*)s1p, row_ptr, csr,
                                                   wseq0, wres1, (uint2*)s2p, outp4);
    stage3_kernel<<<N_NODES / 4, 256, 0, stream>>>((const uint2*)s2p, row_ptr, csr,
                                                   wseq1, outp4);
}